// Round 7
// baseline (565.904 us; speedup 1.0000x reference)
//
#include <hip/hip_runtime.h>
#include <hip/hip_cooperative_groups.h>
#include <math.h>

namespace cg = cooperative_groups;

#define B_SZ 4
#define LSEQ 2048
#define DDIM 768
#define NST  16
#define NROW (B_SZ * LSEQ)      // 8192
#define NJ   33                 // 16 B + 16 C + 1 s1

// ---- fused config ----
#define FNB  768                // blocks (3/CU on 256 CUs)
#define FNT  (FNB * 256)        // 196608 threads
#define FNC  64                 // chunks
#define FCS  (LSEQ / FNC)       // 32
#define FCPG (FNC / 4)          // 16
#define PKS  24                 // proj k-splits: 24*8192 = 196608 threads exactly
#define PKC  (DDIM / PKS)       // 32 floats/slice

// ---- legacy (fallback) config ----
#define NC   128
#define CS   (LSEQ / NC)        // 16
#define KSPL 32
#define KCH  (DDIM / KSPL)      // 24

// ================= shared helpers =================
__device__ __forceinline__ float softplus_f(float z) {
    float t = __expf(-fabsf(z));
    return fmaxf(z, 0.f) + __logf(1.f + t);
}

__device__ __forceinline__ void powers16(float p, float* e) {
    e[0] = p;      e[1] = p * p;      e[2] = e[1] * p;   e[3] = e[1] * e[1];
    e[4] = e[3] * p;  e[5] = e[3] * e[1];  e[6] = e[3] * e[2];  e[7] = e[3] * e[3];
    e[8] = e[7] * p;  e[9] = e[7] * e[1];  e[10] = e[7] * e[2]; e[11] = e[7] * e[3];
    e[12] = e[7] * e[4]; e[13] = e[7] * e[5]; e[14] = e[7] * e[6]; e[15] = e[7] * e[7];
}

__device__ __forceinline__ bool a_structured(const float* acoef) {
    bool st = true;
    #pragma unroll
    for (int n = 0; n < NST; ++n)
        st = st && (fabsf(acoef[n] - (float)(n + 1) * acoef[0]) <= 1e-5f * fabsf(acoef[n]));
    return __all(st) != 0;
}

// ================= fused cooperative kernel =================
__global__ __launch_bounds__(256, 3) void fused_kernel(
    const float* __restrict__ x, const float* __restrict__ A_log,
    const float* __restrict__ Wb, const float* __restrict__ bb,
    const float* __restrict__ Wc, const float* __restrict__ bc,
    const float* __restrict__ W1, const float* __restrict__ b1,
    const float* __restrict__ Wd, const float* __restrict__ bd,
    float* __restrict__ part, float* __restrict__ Bp, float* __restrict__ Cc,
    float* __restrict__ s1, float* __restrict__ Ssum, float* __restrict__ Q,
    float* __restrict__ Hin, float* __restrict__ out)
{
    cg::grid_group grid = cg::this_grid();
    const int tid = threadIdx.x;
    const int bx = blockIdx.x;
    const int gidx = bx * 256 + tid;

    // ---------- phase 0: projection partials ----------
    {
        const int row = gidx & (NROW - 1);
        const int s = gidx >> 13;                 // /8192, 0..23
        const int k0 = s * PKC;
        float4 xv[PKC / 4];                       // 8 float4
        const float* xp0 = x + (size_t)row * DDIM + k0;
        #pragma unroll
        for (int q = 0; q < PKC / 4; ++q) xv[q] = *(const float4*)(xp0 + q * 4);
        #pragma unroll
        for (int j = 0; j < NJ; ++j) {
            const float* wrow = (j < 16) ? (Wb + j * DDIM)
                              : (j < 32) ? (Wc + (j - 16) * DDIM)
                                         : W1;
            const float* wk = wrow + k0;          // lane-invariant -> s_load
            float a = 0.f;
            #pragma unroll
            for (int q = 0; q < PKC / 4; ++q) {
                a = fmaf(xv[q].x, wk[q * 4 + 0], a);
                a = fmaf(xv[q].y, wk[q * 4 + 1], a);
                a = fmaf(xv[q].z, wk[q * 4 + 2], a);
                a = fmaf(xv[q].w, wk[q * 4 + 3], a);
            }
            part[((size_t)s * NJ + j) * NROW + row] = a;
        }
    }
    grid.sync();

    // ---------- phase 0.5: reduce partials ----------
    #pragma unroll
    for (int it = 0; it < 2; ++it) {
        const int idx = gidx + it * FNT;
        if (idx < NJ * NROW) {
            const int j = idx / NROW;
            const int row = idx - j * NROW;
            float a = 0.f;
            #pragma unroll 8
            for (int s = 0; s < PKS; ++s)
                a += part[((size_t)s * NJ + j) * NROW + row];
            if (j < 16)      Bp[(size_t)row * NST + j] = a + bb[j];
            else if (j < 32) Cc[(size_t)row * NST + (j - 16)] = a + bc[j - 16];
            else             s1[row] = a + b1[0];
        }
    }
    grid.sync();

    // ---------- phase A: chunk-local scan (x cached in registers) ----------
    const int d  = (bx % 3) * 256 + tid;
    const int c  = (bx / 3) & (FNC - 1);
    const int b  = bx / (3 * FNC);
    const int rowbase = b * LSEQ + c * FCS;

    const float wd = Wd[d], bdv = bd[d];
    float acoef[NST];
    #pragma unroll
    for (int n = 0; n < NST; ++n) acoef[n] = -__expf(A_log[d * NST + n]);
    const float a0 = acoef[0];
    const bool structured = a_structured(acoef);

    const float4* B4 = (const float4*)(Bp + (size_t)rowbase * NST);
    const float* s1p = s1 + rowbase;

    float xfull[FCS];
    {
        const float* xp = x + (size_t)rowbase * DDIM + d;
        #pragma unroll
        for (int l = 0; l < FCS; ++l) xfull[l] = xp[(size_t)l * DDIM];
    }

    {
        float h[NST];
        #pragma unroll
        for (int n = 0; n < NST; ++n) h[n] = 0.f;
        float S = 0.f;

        if (structured) {
            #pragma unroll 4
            for (int l = 0; l < FCS; ++l) {
                const float delta = softplus_f(fmaf(s1p[l], wd, bdv));
                S += delta;
                float e[NST];
                powers16(__expf(delta * a0), e);
                const float dx = delta * xfull[l];
                const float4 b0 = B4[l * 4 + 0], b1v = B4[l * 4 + 1];
                const float4 b2 = B4[l * 4 + 2], b3v = B4[l * 4 + 3];
                const float bv[NST] = {b0.x, b0.y, b0.z, b0.w, b1v.x, b1v.y, b1v.z, b1v.w,
                                       b2.x, b2.y, b2.z, b2.w, b3v.x, b3v.y, b3v.z, b3v.w};
                #pragma unroll
                for (int n = 0; n < NST; ++n) h[n] = fmaf(e[n], h[n], dx * bv[n]);
            }
        } else {
            #pragma unroll 4
            for (int l = 0; l < FCS; ++l) {
                const float delta = softplus_f(fmaf(s1p[l], wd, bdv));
                S += delta;
                float e[NST];
                #pragma unroll
                for (int n = 0; n < NST; ++n) e[n] = __expf(delta * acoef[n]);
                const float dx = delta * xfull[l];
                const float4 b0 = B4[l * 4 + 0], b1v = B4[l * 4 + 1];
                const float4 b2 = B4[l * 4 + 2], b3v = B4[l * 4 + 3];
                const float bv[NST] = {b0.x, b0.y, b0.z, b0.w, b1v.x, b1v.y, b1v.z, b1v.w,
                                       b2.x, b2.y, b2.z, b2.w, b3v.x, b3v.y, b3v.z, b3v.w};
                #pragma unroll
                for (int n = 0; n < NST; ++n) h[n] = fmaf(e[n], h[n], dx * bv[n]);
            }
        }
        Ssum[((size_t)b * FNC + c) * DDIM + d] = S;
        const size_t gbase = (((size_t)b * FNC + c) * DDIM + d) * NST;
        float4* Q4 = (float4*)(Q + gbase);
        #pragma unroll
        for (int q = 0; q < 4; ++q)
            Q4[q] = make_float4(h[q * 4], h[q * 4 + 1], h[q * 4 + 2], h[q * 4 + 3]);
    }
    grid.sync();

    // ---------- phase B: combine (4-way split + shfl Kogge-Stone) ----------
    {
        const int lane = tid & 63;
        const int rlow = gidx & 15;
        const int g = (gidx >> 4) & 3;
        const int hi = gidx >> 6;
        const int pairIdx = hi * 16 + rlow;           // [0, B*D*N)
        const int bb_ = pairIdx / (DDIM * NST);
        const int r = pairIdx % (DDIM * NST);
        const int dd = r >> 4;
        const float ac = -__expf(A_log[r]);
        const int c0 = g * FCPG;

        float eq[FCPG], qq[FCPG];
        #pragma unroll
        for (int ci = 0; ci < FCPG; ++ci) {
            const size_t base = (size_t)(bb_ * FNC + c0 + ci);
            eq[ci] = __expf(ac * Ssum[base * DDIM + dd]);
            qq[ci] = Q[base * (DDIM * NST) + r];
        }
        float E = 1.f, H = 0.f;
        #pragma unroll
        for (int ci = 0; ci < FCPG; ++ci) { H = fmaf(eq[ci], H, qq[ci]); E *= eq[ci]; }

        float oE = __shfl_up(E, 16, 64);
        float oH = __shfl_up(H, 16, 64);
        if (lane >= 16) { H = fmaf(E, oH, H); E *= oE; }
        oE = __shfl_up(E, 32, 64);
        oH = __shfl_up(H, 32, 64);
        if (lane >= 32) { H = fmaf(E, oH, H); E *= oE; }

        float hin = __shfl_up(H, 16, 64);
        if (g == 0) hin = 0.f;

        float h = hin;
        #pragma unroll
        for (int ci = 0; ci < FCPG; ++ci) {
            const size_t base = (size_t)(bb_ * FNC + c0 + ci);
            Hin[base * (DDIM * NST) + r] = h;
            h = fmaf(eq[ci], h, qq[ci]);
        }
    }
    grid.sync();

    // ---------- phase C: final scan reusing cached x ----------
    {
        const float4* C4 = (const float4*)(Cc + (size_t)rowbase * NST);
        float* yp = out + (size_t)rowbase * DDIM + d;

        float h[NST];
        const size_t gbase = (((size_t)b * FNC + c) * DDIM + d) * NST;
        const float4* H4 = (const float4*)(Hin + gbase);
        #pragma unroll
        for (int q = 0; q < 4; ++q) {
            const float4 hv = H4[q];
            h[q * 4] = hv.x; h[q * 4 + 1] = hv.y; h[q * 4 + 2] = hv.z; h[q * 4 + 3] = hv.w;
        }

        if (structured) {
            #pragma unroll 4
            for (int l = 0; l < FCS; ++l) {
                const float delta = softplus_f(fmaf(s1p[l], wd, bdv));
                float e[NST];
                powers16(__expf(delta * a0), e);
                const float dx = delta * xfull[l];
                const float4 b0 = B4[l * 4 + 0], b1v = B4[l * 4 + 1];
                const float4 b2 = B4[l * 4 + 2], b3v = B4[l * 4 + 3];
                const float4 c0v = C4[l * 4 + 0], c1v = C4[l * 4 + 1];
                const float4 c2v = C4[l * 4 + 2], c3v = C4[l * 4 + 3];
                const float bv[NST] = {b0.x, b0.y, b0.z, b0.w, b1v.x, b1v.y, b1v.z, b1v.w,
                                       b2.x, b2.y, b2.z, b2.w, b3v.x, b3v.y, b3v.z, b3v.w};
                const float cv[NST] = {c0v.x, c0v.y, c0v.z, c0v.w, c1v.x, c1v.y, c1v.z, c1v.w,
                                       c2v.x, c2v.y, c2v.z, c2v.w, c3v.x, c3v.y, c3v.z, c3v.w};
                float y = 0.f;
                #pragma unroll
                for (int n = 0; n < NST; ++n) {
                    h[n] = fmaf(e[n], h[n], dx * bv[n]);
                    y = fmaf(h[n], cv[n], y);
                }
                yp[(size_t)l * DDIM] = y;
            }
        } else {
            #pragma unroll 4
            for (int l = 0; l < FCS; ++l) {
                const float delta = softplus_f(fmaf(s1p[l], wd, bdv));
                float e[NST];
                #pragma unroll
                for (int n = 0; n < NST; ++n) e[n] = __expf(delta * acoef[n]);
                const float dx = delta * xfull[l];
                const float4 b0 = B4[l * 4 + 0], b1v = B4[l * 4 + 1];
                const float4 b2 = B4[l * 4 + 2], b3v = B4[l * 4 + 3];
                const float4 c0v = C4[l * 4 + 0], c1v = C4[l * 4 + 1];
                const float4 c2v = C4[l * 4 + 2], c3v = C4[l * 4 + 3];
                const float bv[NST] = {b0.x, b0.y, b0.z, b0.w, b1v.x, b1v.y, b1v.z, b1v.w,
                                       b2.x, b2.y, b2.z, b2.w, b3v.x, b3v.y, b3v.z, b3v.w};
                const float cv[NST] = {c0v.x, c0v.y, c0v.z, c0v.w, c1v.x, c1v.y, c1v.z, c1v.w,
                                       c2v.x, c2v.y, c2v.z, c2v.w, c3v.x, c3v.y, c3v.z, c3v.w};
                float y = 0.f;
                #pragma unroll
                for (int n = 0; n < NST; ++n) {
                    h[n] = fmaf(e[n], h[n], dx * bv[n]);
                    y = fmaf(h[n], cv[n], y);
                }
                yp[(size_t)l * DDIM] = y;
            }
        }
    }
}

// ================= legacy fallback kernels (round-6, passing) =================
__global__ __launch_bounds__(256) void proj_part_kernel(
    const float* __restrict__ x,
    const float* __restrict__ Wb, const float* __restrict__ Wc,
    const float* __restrict__ W1, float* __restrict__ part)
{
    const int row = blockIdx.x * 256 + threadIdx.x;
    const int s = blockIdx.y;
    const int k0 = s * KCH;
    float4 xv[6];
    const float* xp = x + (size_t)row * DDIM + k0;
    #pragma unroll
    for (int q = 0; q < 6; ++q) xv[q] = *(const float4*)(xp + q * 4);
    float acc[NJ];
    #pragma unroll
    for (int j = 0; j < NJ; ++j) {
        const float* wrow = (j < 16) ? (Wb + j * DDIM)
                          : (j < 32) ? (Wc + (j - 16) * DDIM)
                                     : W1;
        const float* wk = wrow + k0;
        float a = 0.f;
        #pragma unroll
        for (int q = 0; q < 6; ++q) {
            a = fmaf(xv[q].x, wk[q * 4 + 0], a);
            a = fmaf(xv[q].y, wk[q * 4 + 1], a);
            a = fmaf(xv[q].z, wk[q * 4 + 2], a);
            a = fmaf(xv[q].w, wk[q * 4 + 3], a);
        }
        acc[j] = a;
    }
    #pragma unroll
    for (int j = 0; j < NJ; ++j)
        part[((size_t)s * NJ + j) * NROW + row] = acc[j];
}

__global__ __launch_bounds__(256) void proj_reduce_kernel(
    const float* __restrict__ part,
    const float* __restrict__ bb, const float* __restrict__ bc,
    const float* __restrict__ b1,
    float* __restrict__ Bp, float* __restrict__ Cc, float* __restrict__ s1)
{
    const int idx = blockIdx.x * 256 + threadIdx.x;
    if (idx >= NJ * NROW) return;
    const int j = idx / NROW;
    const int row = idx % NROW;
    float a = 0.f;
    #pragma unroll 8
    for (int s = 0; s < KSPL; ++s)
        a += part[((size_t)s * NJ + j) * NROW + row];
    if (j < 16)      Bp[(size_t)row * NST + j] = a + bb[j];
    else if (j < 32) Cc[(size_t)row * NST + (j - 16)] = a + bc[j - 16];
    else             s1[row] = a + b1[0];
}

__global__ __launch_bounds__(256) void pass1_kernel(
    const float* __restrict__ x, const float* __restrict__ A_log,
    const float* __restrict__ Wd, const float* __restrict__ bd,
    const float* __restrict__ Bp, const float* __restrict__ s1,
    float* __restrict__ Ssum, float* __restrict__ Q)
{
    const int tid = threadIdx.x;
    const int d = blockIdx.x * 256 + tid;
    const int c = blockIdx.y, b = blockIdx.z;
    const int rowbase = b * LSEQ + c * CS;
    const float wd = Wd[d], bdv = bd[d];
    float acoef[NST];
    #pragma unroll
    for (int n = 0; n < NST; ++n) acoef[n] = -__expf(A_log[d * NST + n]);
    const float a0 = acoef[0];
    const bool structured = a_structured(acoef);
    const float4* B4 = (const float4*)(Bp + (size_t)rowbase * NST);
    const float* s1p = s1 + rowbase;
    const float* xp = x + (size_t)rowbase * DDIM + d;
    float h[NST];
    #pragma unroll
    for (int n = 0; n < NST; ++n) h[n] = 0.f;
    float S = 0.f;
    if (structured) {
        #pragma unroll 4
        for (int l = 0; l < CS; ++l) {
            const float delta = softplus_f(fmaf(s1p[l], wd, bdv));
            S += delta;
            float e[NST];
            powers16(__expf(delta * a0), e);
            const float dx = delta * xp[(size_t)l * DDIM];
            const float4 b0 = B4[l * 4 + 0], b1v = B4[l * 4 + 1];
            const float4 b2 = B4[l * 4 + 2], b3v = B4[l * 4 + 3];
            const float bv[NST] = {b0.x, b0.y, b0.z, b0.w, b1v.x, b1v.y, b1v.z, b1v.w,
                                   b2.x, b2.y, b2.z, b2.w, b3v.x, b3v.y, b3v.z, b3v.w};
            #pragma unroll
            for (int n = 0; n < NST; ++n) h[n] = fmaf(e[n], h[n], dx * bv[n]);
        }
    } else {
        #pragma unroll 4
        for (int l = 0; l < CS; ++l) {
            const float delta = softplus_f(fmaf(s1p[l], wd, bdv));
            S += delta;
            float e[NST];
            #pragma unroll
            for (int n = 0; n < NST; ++n) e[n] = __expf(delta * acoef[n]);
            const float dx = delta * xp[(size_t)l * DDIM];
            const float4 b0 = B4[l * 4 + 0], b1v = B4[l * 4 + 1];
            const float4 b2 = B4[l * 4 + 2], b3v = B4[l * 4 + 3];
            const float bv[NST] = {b0.x, b0.y, b0.z, b0.w, b1v.x, b1v.y, b1v.z, b1v.w,
                                   b2.x, b2.y, b2.z, b2.w, b3v.x, b3v.y, b3v.z, b3v.w};
            #pragma unroll
            for (int n = 0; n < NST; ++n) h[n] = fmaf(e[n], h[n], dx * bv[n]);
        }
    }
    Ssum[((size_t)b * NC + c) * DDIM + d] = S;
    const size_t gbase = (((size_t)b * NC + c) * DDIM + d) * NST;
    float4* Q4 = (float4*)(Q + gbase);
    #pragma unroll
    for (int q = 0; q < 4; ++q)
        Q4[q] = make_float4(h[q * 4], h[q * 4 + 1], h[q * 4 + 2], h[q * 4 + 3]);
}

#define CPG (NC / 4)
__global__ __launch_bounds__(256) void combine_kernel(
    const float* __restrict__ A_log,
    const float* __restrict__ Ssum, const float* __restrict__ Q,
    float* __restrict__ Hin)
{
    const int gidx = blockIdx.x * 256 + threadIdx.x;
    const int lane = threadIdx.x & 63;
    const int rlow = gidx & 15;
    const int g = (gidx >> 4) & 3;
    const int hi = gidx >> 6;
    const int pairIdx = hi * 16 + rlow;
    const int b = pairIdx / (DDIM * NST);
    const int r = pairIdx % (DDIM * NST);
    const int d = r >> 4;
    const float acoef = -__expf(A_log[r]);
    const int c0 = g * CPG;
    float eq[CPG], qq[CPG];
    #pragma unroll
    for (int ci = 0; ci < CPG; ++ci) {
        const size_t base = (size_t)(b * NC + c0 + ci);
        eq[ci] = __expf(acoef * Ssum[base * DDIM + d]);
        qq[ci] = Q[base * (DDIM * NST) + r];
    }
    float E = 1.f, H = 0.f;
    #pragma unroll
    for (int ci = 0; ci < CPG; ++ci) { H = fmaf(eq[ci], H, qq[ci]); E *= eq[ci]; }
    float oE = __shfl_up(E, 16, 64);
    float oH = __shfl_up(H, 16, 64);
    if (lane >= 16) { H = fmaf(E, oH, H); E *= oE; }
    oE = __shfl_up(E, 32, 64);
    oH = __shfl_up(H, 32, 64);
    if (lane >= 32) { H = fmaf(E, oH, H); E *= oE; }
    float hin = __shfl_up(H, 16, 64);
    if (g == 0) hin = 0.f;
    float h = hin;
    #pragma unroll
    for (int ci = 0; ci < CPG; ++ci) {
        const size_t base = (size_t)(b * NC + c0 + ci);
        Hin[base * (DDIM * NST) + r] = h;
        h = fmaf(eq[ci], h, qq[ci]);
    }
}

__global__ __launch_bounds__(256) void pass2_kernel(
    const float* __restrict__ x, const float* __restrict__ A_log,
    const float* __restrict__ Wd, const float* __restrict__ bd,
    const float* __restrict__ Bp, const float* __restrict__ Cc,
    const float* __restrict__ s1, const float* __restrict__ Hin,
    float* __restrict__ out)
{
    const int tid = threadIdx.x;
    const int d = blockIdx.x * 256 + tid;
    const int c = blockIdx.y, b = blockIdx.z;
    const int rowbase = b * LSEQ + c * CS;
    const float wd = Wd[d], bdv = bd[d];
    float acoef[NST];
    #pragma unroll
    for (int n = 0; n < NST; ++n) acoef[n] = -__expf(A_log[d * NST + n]);
    const float a0 = acoef[0];
    const bool structured = a_structured(acoef);
    const float4* B4 = (const float4*)(Bp + (size_t)rowbase * NST);
    const float4* C4 = (const float4*)(Cc + (size_t)rowbase * NST);
    const float* s1p = s1 + rowbase;
    const float* xp = x + (size_t)rowbase * DDIM + d;
    float* yp = out + (size_t)rowbase * DDIM + d;
    float h[NST];
    const size_t gbase = (((size_t)b * NC + c) * DDIM + d) * NST;
    const float4* H4 = (const float4*)(Hin + gbase);
    #pragma unroll
    for (int q = 0; q < 4; ++q) {
        const float4 hv = H4[q];
        h[q * 4] = hv.x; h[q * 4 + 1] = hv.y; h[q * 4 + 2] = hv.z; h[q * 4 + 3] = hv.w;
    }
    if (structured) {
        #pragma unroll 4
        for (int l = 0; l < CS; ++l) {
            const float delta = softplus_f(fmaf(s1p[l], wd, bdv));
            float e[NST];
            powers16(__expf(delta * a0), e);
            const float dx = delta * xp[(size_t)l * DDIM];
            const float4 b0 = B4[l * 4 + 0], b1v = B4[l * 4 + 1];
            const float4 b2 = B4[l * 4 + 2], b3v = B4[l * 4 + 3];
            const float4 c0 = C4[l * 4 + 0], c1v = C4[l * 4 + 1];
            const float4 c2 = C4[l * 4 + 2], c3v = C4[l * 4 + 3];
            const float bv[NST] = {b0.x, b0.y, b0.z, b0.w, b1v.x, b1v.y, b1v.z, b1v.w,
                                   b2.x, b2.y, b2.z, b2.w, b3v.x, b3v.y, b3v.z, b3v.w};
            const float cv[NST] = {c0.x, c0.y, c0.z, c0.w, c1v.x, c1v.y, c1v.z, c1v.w,
                                   c2.x, c2.y, c2.z, c2.w, c3v.x, c3v.y, c3v.z, c3v.w};
            float y = 0.f;
            #pragma unroll
            for (int n = 0; n < NST; ++n) {
                h[n] = fmaf(e[n], h[n], dx * bv[n]);
                y = fmaf(h[n], cv[n], y);
            }
            yp[(size_t)l * DDIM] = y;
        }
    } else {
        #pragma unroll 4
        for (int l = 0; l < CS; ++l) {
            const float delta = softplus_f(fmaf(s1p[l], wd, bdv));
            float e[NST];
            #pragma unroll
            for (int n = 0; n < NST; ++n) e[n] = __expf(delta * acoef[n]);
            const float dx = delta * xp[(size_t)l * DDIM];
            const float4 b0 = B4[l * 4 + 0], b1v = B4[l * 4 + 1];
            const float4 b2 = B4[l * 4 + 2], b3v = B4[l * 4 + 3];
            const float4 c0 = C4[l * 4 + 0], c1v = C4[l * 4 + 1];
            const float4 c2 = C4[l * 4 + 2], c3v = C4[l * 4 + 3];
            const float bv[NST] = {b0.x, b0.y, b0.z, b0.w, b1v.x, b1v.y, b1v.z, b1v.w,
                                   b2.x, b2.y, b2.z, b2.w, b3v.x, b3v.y, b3v.z, b3v.w};
            const float cv[NST] = {c0.x, c0.y, c0.z, c0.w, c1v.x, c1v.y, c1v.z, c1v.w,
                                   c2.x, c2.y, c2.z, c2.w, c3v.x, c3v.y, c3v.z, c3v.w};
            float y = 0.f;
            #pragma unroll
            for (int n = 0; n < NST; ++n) {
                h[n] = fmaf(e[n], h[n], dx * bv[n]);
                y = fmaf(h[n], cv[n], y);
            }
            yp[(size_t)l * DDIM] = y;
        }
    }
}

extern "C" void kernel_launch(void* const* d_in, const int* in_sizes, int n_in,
                              void* d_out, int out_size, void* d_ws, size_t ws_size,
                              hipStream_t stream) {
    const float* x     = (const float*)d_in[0];
    const float* A_log = (const float*)d_in[1];
    const float* Wb    = (const float*)d_in[2];
    const float* bb    = (const float*)d_in[3];
    const float* Wc    = (const float*)d_in[4];
    const float* bc    = (const float*)d_in[5];
    const float* W1    = (const float*)d_in[6];
    const float* b1    = (const float*)d_in[7];
    const float* Wd    = (const float*)d_in[8];
    const float* bd    = (const float*)d_in[9];
    float* out = (float*)d_out;

    float* ws = (float*)d_ws;
    // layout sized for the larger (legacy) requirements; fused uses prefixes
    const size_t partN = (size_t)KSPL * NJ * NROW;     // 8.65M
    const size_t BpN = (size_t)NROW * NST;
    const size_t s1N = (size_t)NROW;
    const size_t sN  = (size_t)B_SZ * NC * DDIM;       // 393216
    const size_t agg = (size_t)B_SZ * NC * DDIM * NST; // 6.29M

    float* part = ws;
    float* Bp   = part + partN;
    float* Cc   = Bp + BpN;
    float* s1   = Cc + BpN;
    float* Ssum = s1 + s1N;
    float* Q    = Ssum + sN;
    float* Hin  = Q + agg;

    // ---- try single fused cooperative launch ----
    void* args[] = {(void*)&x, (void*)&A_log, (void*)&Wb, (void*)&bb,
                    (void*)&Wc, (void*)&bc, (void*)&W1, (void*)&b1,
                    (void*)&Wd, (void*)&bd,
                    (void*)&part, (void*)&Bp, (void*)&Cc, (void*)&s1,
                    (void*)&Ssum, (void*)&Q, (void*)&Hin, (void*)&out};
    hipError_t err = hipLaunchCooperativeKernel((const void*)fused_kernel,
                                                dim3(FNB), dim3(256),
                                                args, 0, stream);
    if (err == hipSuccess) return;
    (void)hipGetLastError();   // clear sticky error, fall back

    // ---- fallback: 5-kernel path (round-6, passing) ----
    dim3 gproj(NROW / 256, KSPL);
    proj_part_kernel<<<gproj, 256, 0, stream>>>(x, Wb, Wc, W1, part);
    proj_reduce_kernel<<<(NJ * NROW + 255) / 256, 256, 0, stream>>>(part, bb, bc, b1, Bp, Cc, s1);
    dim3 gscan(DDIM / 256, NC, B_SZ);
    pass1_kernel<<<gscan, 256, 0, stream>>>(x, A_log, Wd, bd, Bp, s1, Ssum, Q);
    combine_kernel<<<(B_SZ * DDIM * NST * 4) / 256, 256, 0, stream>>>(A_log, Ssum, Q, Hin);
    pass2_kernel<<<gscan, 256, 0, stream>>>(x, A_log, Wd, bd, Bp, Cc, s1, Hin, out);
}

// Round 8
// 170.505 us; speedup vs baseline: 3.3190x; 3.3190x over previous
//
#include <hip/hip_runtime.h>
#include <math.h>

#define B_SZ 4
#define LSEQ 2048
#define DDIM 768
#define NST  16
#define NROW (B_SZ * LSEQ)      // 8192
#define NJ   33                 // 16 B + 16 C + 1 s1

#define NC   128
#define CS   (LSEQ / NC)        // 16

// ================= projection: thread=(row, k-slice), W via s_load =================
#define KSPL 48
#define KCH  (DDIM / KSPL)      // 16 floats per slice

// grid (NROW/256, KSPL) = (32, 48) = 1536 blocks -> 24 waves/CU. lane = row -> W addr wave-uniform.
__global__ __launch_bounds__(256) void proj_part_kernel(
    const float* __restrict__ x,
    const float* __restrict__ Wb, const float* __restrict__ Wc,
    const float* __restrict__ W1, float* __restrict__ part)
{
    const int row = blockIdx.x * 256 + threadIdx.x;
    const int s = blockIdx.y;
    const int k0 = s * KCH;

    float4 xv[KCH / 4];
    const float* xp = x + (size_t)row * DDIM + k0;
    #pragma unroll
    for (int q = 0; q < KCH / 4; ++q) xv[q] = *(const float4*)(xp + q * 4);

    float acc[NJ];
    #pragma unroll
    for (int j = 0; j < NJ; ++j) {
        const float* wrow = (j < 16) ? (Wb + j * DDIM)
                          : (j < 32) ? (Wc + (j - 16) * DDIM)
                                     : W1;
        const float* wk = wrow + k0;   // lane-invariant -> s_load stream
        float a = 0.f;
        #pragma unroll
        for (int q = 0; q < KCH / 4; ++q) {
            a = fmaf(xv[q].x, wk[q * 4 + 0], a);
            a = fmaf(xv[q].y, wk[q * 4 + 1], a);
            a = fmaf(xv[q].z, wk[q * 4 + 2], a);
            a = fmaf(xv[q].w, wk[q * 4 + 3], a);
        }
        acc[j] = a;
    }
    #pragma unroll
    for (int j = 0; j < NJ; ++j)
        part[((size_t)s * NJ + j) * NROW + row] = acc[j];
}

__global__ __launch_bounds__(256) void proj_reduce_kernel(
    const float* __restrict__ part,
    const float* __restrict__ bb, const float* __restrict__ bc,
    const float* __restrict__ b1,
    float* __restrict__ Bp, float* __restrict__ Cc, float* __restrict__ s1)
{
    const int idx = blockIdx.x * 256 + threadIdx.x;
    if (idx >= NJ * NROW) return;
    const int j = idx / NROW;
    const int row = idx % NROW;
    // 4 partial sums to break the serial add chain
    float a0 = 0.f, a1 = 0.f, a2 = 0.f, a3 = 0.f;
    #pragma unroll 4
    for (int s = 0; s < KSPL; s += 4) {
        a0 += part[((size_t)(s + 0) * NJ + j) * NROW + row];
        a1 += part[((size_t)(s + 1) * NJ + j) * NROW + row];
        a2 += part[((size_t)(s + 2) * NJ + j) * NROW + row];
        a3 += part[((size_t)(s + 3) * NJ + j) * NROW + row];
    }
    const float a = (a0 + a1) + (a2 + a3);
    if (j < 16)      Bp[(size_t)row * NST + j] = a + bb[j];
    else if (j < 32) Cc[(size_t)row * NST + (j - 16)] = a + bc[j - 16];
    else             s1[row] = a + b1[0];
}

// ================= scan =================
__device__ __forceinline__ float softplus_f(float z) {
    float t = __expf(-fabsf(z));
    return fmaxf(z, 0.f) + __logf(1.f + t);
}

__device__ __forceinline__ void powers16(float p, float* e) {
    e[0] = p;      e[1] = p * p;      e[2] = e[1] * p;   e[3] = e[1] * e[1];
    e[4] = e[3] * p;  e[5] = e[3] * e[1];  e[6] = e[3] * e[2];  e[7] = e[3] * e[3];
    e[8] = e[7] * p;  e[9] = e[7] * e[1];  e[10] = e[7] * e[2]; e[11] = e[7] * e[3];
    e[12] = e[7] * e[4]; e[13] = e[7] * e[5]; e[14] = e[7] * e[6]; e[15] = e[7] * e[7];
}

__device__ __forceinline__ bool a_structured(const float* acoef) {
    bool st = true;
    #pragma unroll
    for (int n = 0; n < NST; ++n)
        st = st && (fabsf(acoef[n] - (float)(n + 1) * acoef[0]) <= 1e-5f * fabsf(acoef[n]));
    return __all(st) != 0;
}

__global__ __launch_bounds__(256) void pass1_kernel(
    const float* __restrict__ x, const float* __restrict__ A_log,
    const float* __restrict__ Wd, const float* __restrict__ bd,
    const float* __restrict__ Bp, const float* __restrict__ s1,
    float* __restrict__ Ssum, float* __restrict__ Q)
{
    const int tid = threadIdx.x;
    const int d = blockIdx.x * 256 + tid;
    const int c = blockIdx.y, b = blockIdx.z;
    const int rowbase = b * LSEQ + c * CS;

    const float wd = Wd[d], bdv = bd[d];
    float acoef[NST];
    #pragma unroll
    for (int n = 0; n < NST; ++n) acoef[n] = -__expf(A_log[d * NST + n]);
    const float a0 = acoef[0];
    const bool structured = a_structured(acoef);

    const float4* B4 = (const float4*)(Bp + (size_t)rowbase * NST);
    const float* s1p = s1 + rowbase;
    const float* xp = x + (size_t)rowbase * DDIM + d;

    float h[NST];
    #pragma unroll
    for (int n = 0; n < NST; ++n) h[n] = 0.f;
    float S0 = 0.f, S1 = 0.f, S2 = 0.f, S3 = 0.f;

    float xv = xp[0];   // prefetch
    if (structured) {
        #pragma unroll
        for (int l = 0; l < CS; ++l) {
            const float xnext = (l + 1 < CS) ? xp[(size_t)(l + 1) * DDIM] : 0.f;
            const float delta = softplus_f(fmaf(s1p[l], wd, bdv));
            if ((l & 3) == 0) S0 += delta; else if ((l & 3) == 1) S1 += delta;
            else if ((l & 3) == 2) S2 += delta; else S3 += delta;
            float e[NST];
            powers16(__expf(delta * a0), e);
            const float dx = delta * xv;
            const float4 b0 = B4[l * 4 + 0], b1v = B4[l * 4 + 1];
            const float4 b2 = B4[l * 4 + 2], b3v = B4[l * 4 + 3];
            const float bv[NST] = {b0.x, b0.y, b0.z, b0.w, b1v.x, b1v.y, b1v.z, b1v.w,
                                   b2.x, b2.y, b2.z, b2.w, b3v.x, b3v.y, b3v.z, b3v.w};
            #pragma unroll
            for (int n = 0; n < NST; ++n) h[n] = fmaf(e[n], h[n], dx * bv[n]);
            xv = xnext;
        }
    } else {
        #pragma unroll
        for (int l = 0; l < CS; ++l) {
            const float xnext = (l + 1 < CS) ? xp[(size_t)(l + 1) * DDIM] : 0.f;
            const float delta = softplus_f(fmaf(s1p[l], wd, bdv));
            if ((l & 3) == 0) S0 += delta; else if ((l & 3) == 1) S1 += delta;
            else if ((l & 3) == 2) S2 += delta; else S3 += delta;
            float e[NST];
            #pragma unroll
            for (int n = 0; n < NST; ++n) e[n] = __expf(delta * acoef[n]);
            const float dx = delta * xv;
            const float4 b0 = B4[l * 4 + 0], b1v = B4[l * 4 + 1];
            const float4 b2 = B4[l * 4 + 2], b3v = B4[l * 4 + 3];
            const float bv[NST] = {b0.x, b0.y, b0.z, b0.w, b1v.x, b1v.y, b1v.z, b1v.w,
                                   b2.x, b2.y, b2.z, b2.w, b3v.x, b3v.y, b3v.z, b3v.w};
            #pragma unroll
            for (int n = 0; n < NST; ++n) h[n] = fmaf(e[n], h[n], dx * bv[n]);
            xv = xnext;
        }
    }
    Ssum[((size_t)b * NC + c) * DDIM + d] = (S0 + S1) + (S2 + S3);
    const size_t gbase = (((size_t)b * NC + c) * DDIM + d) * NST;
    float4* Q4 = (float4*)(Q + gbase);
    #pragma unroll
    for (int q = 0; q < 4; ++q)
        Q4[q] = make_float4(h[q * 4], h[q * 4 + 1], h[q * 4 + 2], h[q * 4 + 3]);
}

// ---------- combine: 4-way split of the chunk scan + shfl compose ----------
#define CPG (NC / 4)   // 32 chunks per group
__global__ __launch_bounds__(256) void combine_kernel(
    const float* __restrict__ A_log,
    const float* __restrict__ Ssum, const float* __restrict__ Q,
    float* __restrict__ Hin)
{
    const int gidx = blockIdx.x * 256 + threadIdx.x;  // over B*D*N*4 = 196608
    const int lane = threadIdx.x & 63;
    const int rlow = gidx & 15;
    const int g = (gidx >> 4) & 3;
    const int hi = gidx >> 6;
    const int pairIdx = hi * 16 + rlow;               // [0, B*D*N)
    const int b = pairIdx / (DDIM * NST);
    const int r = pairIdx % (DDIM * NST);
    const int d = r >> 4;
    const float acoef = -__expf(A_log[r]);
    const int c0 = g * CPG;

    float eq[CPG], qq[CPG];
    #pragma unroll
    for (int ci = 0; ci < CPG; ++ci) {
        const size_t base = (size_t)(b * NC + c0 + ci);
        eq[ci] = __expf(acoef * Ssum[base * DDIM + d]);
        qq[ci] = Q[base * (DDIM * NST) + r];
    }
    float E = 1.f, H = 0.f;
    #pragma unroll
    for (int ci = 0; ci < CPG; ++ci) { H = fmaf(eq[ci], H, qq[ci]); E *= eq[ci]; }

    float oE = __shfl_up(E, 16, 64);
    float oH = __shfl_up(H, 16, 64);
    if (lane >= 16) { H = fmaf(E, oH, H); E *= oE; }
    oE = __shfl_up(E, 32, 64);
    oH = __shfl_up(H, 32, 64);
    if (lane >= 32) { H = fmaf(E, oH, H); E *= oE; }

    float hin = __shfl_up(H, 16, 64);   // exclusive
    if (g == 0) hin = 0.f;

    float h = hin;
    #pragma unroll
    for (int ci = 0; ci < CPG; ++ci) {
        const size_t base = (size_t)(b * NC + c0 + ci);
        Hin[base * (DDIM * NST) + r] = h;
        h = fmaf(eq[ci], h, qq[ci]);
    }
}

__global__ __launch_bounds__(256) void pass2_kernel(
    const float* __restrict__ x, const float* __restrict__ A_log,
    const float* __restrict__ Wd, const float* __restrict__ bd,
    const float* __restrict__ Bp, const float* __restrict__ Cc,
    const float* __restrict__ s1, const float* __restrict__ Hin,
    float* __restrict__ out)
{
    const int tid = threadIdx.x;
    const int d = blockIdx.x * 256 + tid;
    const int c = blockIdx.y, b = blockIdx.z;
    const int rowbase = b * LSEQ + c * CS;

    const float wd = Wd[d], bdv = bd[d];
    float acoef[NST];
    #pragma unroll
    for (int n = 0; n < NST; ++n) acoef[n] = -__expf(A_log[d * NST + n]);
    const float a0 = acoef[0];
    const bool structured = a_structured(acoef);

    const float4* B4 = (const float4*)(Bp + (size_t)rowbase * NST);
    const float4* C4 = (const float4*)(Cc + (size_t)rowbase * NST);
    const float* s1p = s1 + rowbase;
    const float* xp = x + (size_t)rowbase * DDIM + d;
    float* yp = out + (size_t)rowbase * DDIM + d;

    float h[NST];
    const size_t gbase = (((size_t)b * NC + c) * DDIM + d) * NST;
    const float4* H4 = (const float4*)(Hin + gbase);
    #pragma unroll
    for (int q = 0; q < 4; ++q) {
        const float4 hv = H4[q];
        h[q * 4] = hv.x; h[q * 4 + 1] = hv.y; h[q * 4 + 2] = hv.z; h[q * 4 + 3] = hv.w;
    }

    float xv = xp[0];   // prefetch
    if (structured) {
        #pragma unroll
        for (int l = 0; l < CS; ++l) {
            const float xnext = (l + 1 < CS) ? xp[(size_t)(l + 1) * DDIM] : 0.f;
            const float delta = softplus_f(fmaf(s1p[l], wd, bdv));
            float e[NST];
            powers16(__expf(delta * a0), e);
            const float dx = delta * xv;
            const float4 b0 = B4[l * 4 + 0], b1v = B4[l * 4 + 1];
            const float4 b2 = B4[l * 4 + 2], b3v = B4[l * 4 + 3];
            const float4 c0 = C4[l * 4 + 0], c1v = C4[l * 4 + 1];
            const float4 c2 = C4[l * 4 + 2], c3v = C4[l * 4 + 3];
            const float bv[NST] = {b0.x, b0.y, b0.z, b0.w, b1v.x, b1v.y, b1v.z, b1v.w,
                                   b2.x, b2.y, b2.z, b2.w, b3v.x, b3v.y, b3v.z, b3v.w};
            const float cv[NST] = {c0.x, c0.y, c0.z, c0.w, c1v.x, c1v.y, c1v.z, c1v.w,
                                   c2.x, c2.y, c2.z, c2.w, c3v.x, c3v.y, c3v.z, c3v.w};
            // 4 partial y accumulators break the 16-deep serial fma chain
            float y0 = 0.f, y1 = 0.f, y2 = 0.f, y3 = 0.f;
            #pragma unroll
            for (int q = 0; q < 4; ++q) {
                h[q*4+0] = fmaf(e[q*4+0], h[q*4+0], dx * bv[q*4+0]);
                h[q*4+1] = fmaf(e[q*4+1], h[q*4+1], dx * bv[q*4+1]);
                h[q*4+2] = fmaf(e[q*4+2], h[q*4+2], dx * bv[q*4+2]);
                h[q*4+3] = fmaf(e[q*4+3], h[q*4+3], dx * bv[q*4+3]);
            }
            #pragma unroll
            for (int q = 0; q < 4; ++q) {
                y0 = fmaf(h[q*4+0], cv[q*4+0], y0);
                y1 = fmaf(h[q*4+1], cv[q*4+1], y1);
                y2 = fmaf(h[q*4+2], cv[q*4+2], y2);
                y3 = fmaf(h[q*4+3], cv[q*4+3], y3);
            }
            yp[(size_t)l * DDIM] = (y0 + y1) + (y2 + y3);
            xv = xnext;
        }
    } else {
        #pragma unroll
        for (int l = 0; l < CS; ++l) {
            const float xnext = (l + 1 < CS) ? xp[(size_t)(l + 1) * DDIM] : 0.f;
            const float delta = softplus_f(fmaf(s1p[l], wd, bdv));
            float e[NST];
            #pragma unroll
            for (int n = 0; n < NST; ++n) e[n] = __expf(delta * acoef[n]);
            const float dx = delta * xv;
            const float4 b0 = B4[l * 4 + 0], b1v = B4[l * 4 + 1];
            const float4 b2 = B4[l * 4 + 2], b3v = B4[l * 4 + 3];
            const float4 c0 = C4[l * 4 + 0], c1v = C4[l * 4 + 1];
            const float4 c2 = C4[l * 4 + 2], c3v = C4[l * 4 + 3];
            const float bv[NST] = {b0.x, b0.y, b0.z, b0.w, b1v.x, b1v.y, b1v.z, b1v.w,
                                   b2.x, b2.y, b2.z, b2.w, b3v.x, b3v.y, b3v.z, b3v.w};
            const float cv[NST] = {c0.x, c0.y, c0.z, c0.w, c1v.x, c1v.y, c1v.z, c1v.w,
                                   c2.x, c2.y, c2.z, c2.w, c3v.x, c3v.y, c3v.z, c3v.w};
            float y0 = 0.f, y1 = 0.f, y2 = 0.f, y3 = 0.f;
            #pragma unroll
            for (int n = 0; n < NST; ++n) h[n] = fmaf(e[n], h[n], dx * bv[n]);
            #pragma unroll
            for (int q = 0; q < 4; ++q) {
                y0 = fmaf(h[q*4+0], cv[q*4+0], y0);
                y1 = fmaf(h[q*4+1], cv[q*4+1], y1);
                y2 = fmaf(h[q*4+2], cv[q*4+2], y2);
                y3 = fmaf(h[q*4+3], cv[q*4+3], y3);
            }
            yp[(size_t)l * DDIM] = (y0 + y1) + (y2 + y3);
            xv = xnext;
        }
    }
}

extern "C" void kernel_launch(void* const* d_in, const int* in_sizes, int n_in,
                              void* d_out, int out_size, void* d_ws, size_t ws_size,
                              hipStream_t stream) {
    const float* x     = (const float*)d_in[0];
    const float* A_log = (const float*)d_in[1];
    const float* Wb    = (const float*)d_in[2];
    const float* bb    = (const float*)d_in[3];
    const float* Wc    = (const float*)d_in[4];
    const float* bc    = (const float*)d_in[5];
    const float* W1    = (const float*)d_in[6];
    const float* b1    = (const float*)d_in[7];
    const float* Wd    = (const float*)d_in[8];
    const float* bd    = (const float*)d_in[9];
    float* out = (float*)d_out;

    float* ws = (float*)d_ws;
    const size_t partN = (size_t)KSPL * NJ * NROW;     // 12.98M floats = 51.9MB
    const size_t BpN = (size_t)NROW * NST;
    const size_t s1N = (size_t)NROW;
    const size_t sN  = (size_t)B_SZ * NC * DDIM;       // 393216
    const size_t agg = (size_t)B_SZ * NC * DDIM * NST; // 6.29M

    float* part = ws;
    float* Bp   = part + partN;
    float* Cc   = Bp + BpN;
    float* s1   = Cc + BpN;
    float* Ssum = s1 + s1N;
    float* Q    = Ssum + sN;
    float* Hin  = Q + agg;

    dim3 gproj(NROW / 256, KSPL);
    proj_part_kernel<<<gproj, 256, 0, stream>>>(x, Wb, Wc, W1, part);
    proj_reduce_kernel<<<(NJ * NROW + 255) / 256, 256, 0, stream>>>(part, bb, bc, b1, Bp, Cc, s1);

    dim3 gscan(DDIM / 256, NC, B_SZ);
    pass1_kernel<<<gscan, 256, 0, stream>>>(x, A_log, Wd, bd, Bp, s1, Ssum, Q);

    combine_kernel<<<(B_SZ * DDIM * NST * 4) / 256, 256, 0, stream>>>(A_log, Ssum, Q, Hin);

    pass2_kernel<<<gscan, 256, 0, stream>>>(x, A_log, Wd, bd, Bp, Cc, s1, Hin, out);
}